// Round 5
// baseline (358.157 us; speedup 1.0000x reference)
//
#include <hip/hip_runtime.h>

#define N_TOK 4096
#define DMODEL 1024
#define NEXP 16
#define HDIM 2048
#define CAP 1024

typedef __attribute__((ext_vector_type(8))) short frag8;      // 8 bf16 (4 VGPR) MFMA operand
typedef __attribute__((ext_vector_type(4))) float f32x4;      // MFMA accumulator
typedef __attribute__((ext_vector_type(8))) unsigned short us8;

__device__ __forceinline__ unsigned short f2bf(float x) {
  unsigned u = __builtin_bit_cast(unsigned, x);
  u += 0x7fffu + ((u >> 16) & 1u);           // RNE
  return (unsigned short)(u >> 16);
}

__device__ __forceinline__ void load_lds16(const void* g, void* l) {
  __builtin_amdgcn_global_load_lds((const __attribute__((address_space(1))) void*)g,
                                   (__attribute__((address_space(3))) void*)l, 16, 0, 0);
}

// ---------------- gate phase 1: logits -> top2 -> softmax (NO atomics) ----------------
__global__ __launch_bounds__(256) void gate_logits_kernel(
    const float* __restrict__ x, const float* __restrict__ Wg, const float* __restrict__ bg,
    int* __restrict__ a_e, float* __restrict__ a_gate)
{
  int wid = threadIdx.x >> 6, l = threadIdx.x & 63;
  int n = blockIdx.x * 4 + wid;
  const float* xr = x + (size_t)n * DMODEL;
  float acc[NEXP];
#pragma unroll
  for (int e = 0; e < NEXP; ++e) acc[e] = 0.f;
#pragma unroll
  for (int q = 0; q < 4; ++q) {
    float4 xv = *(const float4*)(xr + q * 256 + l * 4);
    const float* wr = Wg + (size_t)(q * 256 + l * 4) * NEXP;
#pragma unroll
    for (int j = 0; j < 4; ++j) {
      float xs = j == 0 ? xv.x : j == 1 ? xv.y : j == 2 ? xv.z : xv.w;
      const float4* w4 = (const float4*)(wr + j * NEXP);
#pragma unroll
      for (int qq = 0; qq < 4; ++qq) {
        float4 w = w4[qq];
        acc[qq*4+0] += xs * w.x; acc[qq*4+1] += xs * w.y;
        acc[qq*4+2] += xs * w.z; acc[qq*4+3] += xs * w.w;
      }
    }
  }
#pragma unroll
  for (int e = 0; e < NEXP; ++e) {
    float v = acc[e];
#pragma unroll
    for (int off = 32; off > 0; off >>= 1) v += __shfl_xor(v, off, 64);
    acc[e] = v + bg[e];
  }
  if (l == 0) {
    int i1 = 0; float v1 = acc[0];
#pragma unroll
    for (int e = 1; e < NEXP; ++e) if (acc[e] > v1) { v1 = acc[e]; i1 = e; }
    int i2 = -1; float v2 = -1e30f;
#pragma unroll
    for (int e = 0; e < NEXP; ++e) if (e != i1 && acc[e] > v2) { v2 = acc[e]; i2 = e; }
    float e2 = __expf(v2 - v1);
    float inv = 1.f / (1.f + e2);
    a_e[n*2] = i1;   a_gate[n*2] = inv;
    a_e[n*2+1] = i2; a_gate[n*2+1] = e2 * inv;
  }
}

// ---------------- gate phase 2: per-expert slot assignment via LDS counter ----------------
__global__ __launch_bounds__(256) void assign_kernel(
    const int* __restrict__ a_e, int* __restrict__ a_slot,
    int* __restrict__ tok_of_slot, int* __restrict__ cnt)
{
  __shared__ int c;
  if (threadIdx.x == 0) c = 0;
  __syncthreads();
  int eid = blockIdx.x;
  for (int j = threadIdx.x; j < N_TOK * 2; j += 256) {
    if (a_e[j] == eid) {
      int p = atomicAdd(&c, 1);
      a_slot[j] = p;
      if (p < CAP) tok_of_slot[eid * CAP + p] = j >> 1;
    }
  }
  __syncthreads();
  if (threadIdx.x == 0) cnt[eid] = c;
}

// ---------------- grouped GEMM, 128x128 tile, 4 waves, 64KB LDS (2 blocks/CU) ----------------
// A: GATHER_A ? gather f32 x rows via tok_of_slot : blocked bf16 [e][rt:8][c:KTB][128][64]
// B: W row-major f32 [e][KTB*64][NTILES*128], reg-staged -> bf16 swizzled LDS image
template<int KTB, int NTILES, bool GATHER_A, bool GELU, bool OUT_BLOCKED>
__global__ __launch_bounds__(256, 2) void gemm_kernel(
    const unsigned short* __restrict__ Ablk, const float* __restrict__ x,
    const int* __restrict__ tok_of_slot, const float* __restrict__ W,
    void* __restrict__ OutP, const float* __restrict__ bias, const int* __restrict__ cnt)
{
  constexpr int LDW = NTILES * 128;
  __shared__ __align__(16) char smem_b[65536];   // A dbuf 2x16KB | B dbuf 2x16KB
  int bid = blockIdx.x;
  int e = bid / (8 * NTILES), rem = bid % (8 * NTILES);
  int mt = rem / NTILES, nt = rem % NTILES;      // mt stride NTILES (mult of 8) => mt-siblings same XCD
  int mcnt = cnt[e]; if (mcnt > CAP) mcnt = CAP;
  if (mt * 128 >= mcnt) return;
  int t = threadIdx.x, l = t & 63, wid = t >> 6;
  int wm = wid >> 1, wn = wid & 1;
  int rA = l & 15, g = l >> 4, r7 = rA & 7;
  int swz0 = (g ^ r7) << 4, swz1 = ((g + 4) ^ r7) << 4;
  int e8 = e * 8;

  // ---- B staging map: thread -> n rows {2*(t&63), +1}, k run 16 at (t>>6)*16 ----
  int bn0 = 2 * (t & 63);
  int bk0 = (t >> 6) * 16;
  const float* wbase = W + (size_t)e * (KTB * 64) * LDW + (size_t)nt * 128 + bn0;
  float2 br[16];
  auto loadB = [&](int kt) {
    const float* p = wbase + (size_t)(kt * 64 + bk0) * LDW;
#pragma unroll
    for (int j = 0; j < 16; ++j) br[j] = *(const float2*)(p + (size_t)j * LDW);
  };
  auto writeB = [&](int bv) {
    char* lB = smem_b + 32768 + bv * 16384;
#pragma unroll
    for (int rr = 0; rr < 2; ++rr) {
      int row = bn0 + rr;
      char* rowp = lB + row * 128;
#pragma unroll
      for (int gg = 0; gg < 2; ++gg) {
        us8 p8;
#pragma unroll
        for (int j = 0; j < 8; ++j) p8[j] = f2bf(rr ? br[gg*8+j].y : br[gg*8+j].x);
        int g8 = (bk0 >> 3) + gg;
        *(us8*)(rowp + ((g8 ^ (row & 7)) << 4)) = p8;
      }
    }
  };

  // ---- A staging (GATHER mode): thread -> row t&127, k run 32 at (t>>7)*32 ----
  int am = t & 127;
  int ak0 = (t >> 7) * 32;
  int slot = mt * 128 + am;
  const float* xbase = nullptr;
  float4 ar[8];
  if (GATHER_A) {
    int tokid = (slot < mcnt) ? tok_of_slot[e * CAP + slot] : 0;
    xbase = x + (size_t)tokid * DMODEL + ak0;
  }
  auto loadA = [&](int kt) {
#pragma unroll
    for (int j = 0; j < 8; ++j) ar[j] = *(const float4*)(xbase + kt * 64 + j * 4);
  };
  auto writeA = [&](int bv) {
    char* lA = smem_b + bv * 16384;
    char* rowp = lA + am * 128;
    int a7 = am & 7;
#pragma unroll
    for (int gg = 0; gg < 4; ++gg) {
      us8 p8;
      float4 u = ar[gg*2], v = ar[gg*2+1];
      p8[0]=f2bf(u.x); p8[1]=f2bf(u.y); p8[2]=f2bf(u.z); p8[3]=f2bf(u.w);
      p8[4]=f2bf(v.x); p8[5]=f2bf(v.y); p8[6]=f2bf(v.z); p8[7]=f2bf(v.w);
      int g8 = (ak0 >> 3) + gg;
      *(us8*)(rowp + ((g8 ^ a7) << 4)) = p8;
    }
  };
  // ---- A staging (BLOCKED mode): 16KB linear copy via global_load_lds ----
  auto stageAblk = [&](int bv, int kt) {
    const unsigned short* s = Ablk + ((size_t)(e8 + mt) * KTB + kt) * 8192;
    char* lA = smem_b + bv * 16384;
    load_lds16(s + (size_t)t * 8,        lA + wid * 1024);
    load_lds16(s + 2048 + (size_t)t * 8, lA + 4096 + wid * 1024);
    load_lds16(s + 4096 + (size_t)t * 8, lA + 8192 + wid * 1024);
    load_lds16(s + 6144 + (size_t)t * 8, lA + 12288 + wid * 1024);
  };

  f32x4 acc[4][4] = {};
  int aRow = (wm * 64 + rA) * 128;
  int bRow = (wn * 64 + rA) * 128;

  // prologue
  if (GATHER_A) { loadA(0); loadB(0); writeA(0); writeB(0); }
  else          { loadB(0); stageAblk(0, 0); writeB(0); }
  __syncthreads();

  int buf = 0;
  for (int kt = 0; kt < KTB; ++kt) {
    bool more = (kt + 1 < KTB);
    if (more) {                                   // issue-early (T14)
      if (GATHER_A) { loadA(kt + 1); loadB(kt + 1); }
      else          { loadB(kt + 1); stageAblk(buf ^ 1, kt + 1); }
    }
    const char* bA = smem_b + buf * 16384 + aRow;
    const char* bB = smem_b + 32768 + buf * 16384 + bRow;
    frag8 bfr[4][2];
#pragma unroll
    for (int n16 = 0; n16 < 4; ++n16) {
      bfr[n16][0] = *(const frag8*)(bB + n16 * 2048 + swz0);
      bfr[n16][1] = *(const frag8*)(bB + n16 * 2048 + swz1);
    }
    __builtin_amdgcn_s_setprio(1);
#pragma unroll
    for (int m16 = 0; m16 < 4; ++m16) {
      frag8 a0 = *(const frag8*)(bA + m16 * 2048 + swz0);
      frag8 a1 = *(const frag8*)(bA + m16 * 2048 + swz1);
#pragma unroll
      for (int n16 = 0; n16 < 4; ++n16) {
        acc[m16][n16] = __builtin_amdgcn_mfma_f32_16x16x32_bf16(a0, bfr[n16][0], acc[m16][n16], 0, 0, 0);
        acc[m16][n16] = __builtin_amdgcn_mfma_f32_16x16x32_bf16(a1, bfr[n16][1], acc[m16][n16], 0, 0, 0);
      }
    }
    __builtin_amdgcn_s_setprio(0);
    if (more) {                                   // write-late (T14)
      if (GATHER_A) writeA(buf ^ 1);
      writeB(buf ^ 1);
    }
    __syncthreads();
    buf ^= 1;
  }

  float bv[4];
#pragma unroll
  for (int n16 = 0; n16 < 4; ++n16)
    bv[n16] = bias[e * LDW + nt * 128 + wn * 64 + n16 * 16 + rA];

  if (OUT_BLOCKED) {
    __syncthreads();                              // all frag reads done; reuse smem as bounce
    char* wb = smem_b + wid * 8192;               // per-wave 64x64 bf16 image
#pragma unroll
    for (int m16 = 0; m16 < 4; ++m16)
#pragma unroll
      for (int n16 = 0; n16 < 4; ++n16)
#pragma unroll
        for (int rr = 0; rr < 4; ++rr) {
          float xv = acc[m16][n16][rr] + bv[n16];
          if (GELU) {
            float u = 0.7978845608028654f * (xv + 0.044715f * xv * xv * xv);
            xv = xv / (1.f + __expf(-2.f * u));   // x*sigmoid(2u) == gelu_tanh
          }
          int rowl = m16 * 16 + g * 4 + rr;       // 0..63
          int col  = n16 * 16 + rA;               // 0..63
          *(unsigned short*)(wb + rowl * 128 + (((col >> 3) ^ (rowl & 7)) << 4) + (col & 7) * 2) = f2bf(xv);
        }
    asm volatile("s_waitcnt lgkmcnt(0)" ::: "memory");
    unsigned short* Out = (unsigned short*)OutP;  // blocked [e][mt:8][chunk:2*NTILES][128][64]
    size_t ob = ((size_t)(e8 + mt) * (2 * NTILES) + nt * 2 + wn) * 8192;
#pragma unroll
    for (int it = 0; it < 8; ++it) {
      int row = it * 8 + (l >> 3), p = l & 7;     // phys slot == out phys slot (XORs cancel)
      us8 v = *(const us8*)(wb + row * 128 + p * 16);
      *(us8*)&Out[ob + (size_t)(wm * 64 + row) * 64 + p * 8] = v;
    }
  } else {
    float* Out = (float*)OutP;                    // linear f32 [e][CAP][LDW]
#pragma unroll
    for (int m16 = 0; m16 < 4; ++m16)
#pragma unroll
      for (int n16 = 0; n16 < 4; ++n16) {
        int col = nt * 128 + wn * 64 + n16 * 16 + rA;
#pragma unroll
        for (int rr = 0; rr < 4; ++rr) {
          int row = mt * 128 + wm * 64 + m16 * 16 + g * 4 + rr;
          Out[(size_t)(e * CAP + row) * LDW + col] = acc[m16][n16][rr] + bv[n16];
        }
      }
  }
}

// ---------------- combine: out[n] = g0*ye[e0][s0] + g1*ye[e1][s1] ----------------
__global__ __launch_bounds__(256) void combine_kernel(
    const float* __restrict__ ye, const int* __restrict__ a_e, const int* __restrict__ a_slot,
    const float* __restrict__ a_gate, float* __restrict__ out)
{
  int n = blockIdx.x, t = threadIdx.x;
  int e0 = a_e[n*2], e1 = a_e[n*2+1];
  int s0 = a_slot[n*2], s1 = a_slot[n*2+1];
  float g0 = a_gate[n*2], g1 = a_gate[n*2+1];
  float rx = 0.f, ry = 0.f, rz = 0.f, rw = 0.f;
  if (s0 < CAP) {
    float4 v = *(const float4*)&ye[(size_t)(e0*CAP + s0)*DMODEL + t*4];
    rx += g0*v.x; ry += g0*v.y; rz += g0*v.z; rw += g0*v.w;
  }
  if (s1 < CAP) {
    float4 v = *(const float4*)&ye[(size_t)(e1*CAP + s1)*DMODEL + t*4];
    rx += g1*v.x; ry += g1*v.y; rz += g1*v.z; rw += g1*v.w;
  }
  float4 o; o.x = rx; o.y = ry; o.z = rz; o.w = rw;
  *(float4*)&out[(size_t)n*DMODEL + t*4] = o;
}

extern "C" void kernel_launch(void* const* d_in, const int* in_sizes, int n_in,
                              void* d_out, int out_size, void* d_ws, size_t ws_size,
                              hipStream_t stream) {
  const float* x  = (const float*)d_in[0];
  const float* Wg = (const float*)d_in[1];
  const float* bg = (const float*)d_in[2];
  const float* W1 = (const float*)d_in[3];
  const float* b1 = (const float*)d_in[4];
  const float* W2 = (const float*)d_in[5];
  const float* b2 = (const float*)d_in[6];
  float* out = (float*)d_out;
  char* ws = (char*)d_ws;

  // workspace layout (~134MB)
  unsigned short* hB  = (unsigned short*)(ws);                 // 67,108,864 B  bf16 blocked
  float* ye           = (float*)(ws + 67108864);               // 67,108,864 B  f32 linear
  int* cnt            = (int*)(ws + 134217728);                // 64 B
  int* tok            = (int*)(ws + 134217792);                // 65,536 B
  int* a_e            = (int*)(ws + 134283328);                // 32,768 B
  int* a_slot         = (int*)(ws + 134316096);                // 32,768 B
  float* a_gate       = (float*)(ws + 134348864);              // 32,768 B

  gate_logits_kernel<<<1024, 256, 0, stream>>>(x, Wg, bg, a_e, a_gate);
  assign_kernel<<<16, 256, 0, stream>>>(a_e, a_slot, tok, cnt);
  // gemm1: gather x rows via tok + W1 f32 direct -> hB blocked bf16 + gelu; 128x128 tiles
  gemm_kernel<16, 16, true, true, true><<<2048, 256, 0, stream>>>(
      nullptr, x, tok, W1, (void*)hB, b1, cnt);
  // gemm2: hB blocked bf16 + W2 f32 direct -> ye linear f32; 128x128 tiles
  gemm_kernel<32, 8, false, false, false><<<1024, 256, 0, stream>>>(
      hB, nullptr, nullptr, W2, (void*)ye, b2, cnt);
  combine_kernel<<<4096, 256, 0, stream>>>(ye, a_e, a_slot, a_gate, out);
}

// Round 6
// 285.207 us; speedup vs baseline: 1.2558x; 1.2558x over previous
//
#include <hip/hip_runtime.h>

#define N_TOK 4096
#define DMODEL 1024
#define NEXP 16
#define HDIM 2048
#define CAP 1024

// swizzle: phys 16B-slot within a 64B row = content_slot ^ SIG(row); 2-way-optimal
#define SIG(row) ((((row) >> 1) & 2) | (((row) >> 2) & 1))

typedef __attribute__((ext_vector_type(8))) short frag8;      // 8 bf16 MFMA operand
typedef __attribute__((ext_vector_type(4))) float f32x4;      // MFMA accumulator
typedef __attribute__((ext_vector_type(8))) unsigned short us8;

__device__ __forceinline__ unsigned short f2bf(float x) {
  unsigned u = __builtin_bit_cast(unsigned, x);
  u += 0x7fffu + ((u >> 16) & 1u);           // RNE
  return (unsigned short)(u >> 16);
}
__device__ __forceinline__ float bf2f(unsigned short b) {
  unsigned u = ((unsigned)b) << 16;
  return __builtin_bit_cast(float, u);
}

__device__ __forceinline__ void load_lds16(const void* g, void* l) {
  __builtin_amdgcn_global_load_lds((const __attribute__((address_space(1))) void*)g,
                                   (__attribute__((address_space(3))) void*)l, 16, 0, 0);
}

// ---------------- gate phase 1: logits -> top2 -> softmax (NO atomics) ----------------
__global__ __launch_bounds__(256) void gate_logits_kernel(
    const float* __restrict__ x, const float* __restrict__ Wg, const float* __restrict__ bg,
    int* __restrict__ a_e, float* __restrict__ a_gate)
{
  int wid = threadIdx.x >> 6, l = threadIdx.x & 63;
  int n = blockIdx.x * 4 + wid;
  const float* xr = x + (size_t)n * DMODEL;
  float acc[NEXP];
#pragma unroll
  for (int e = 0; e < NEXP; ++e) acc[e] = 0.f;
#pragma unroll
  for (int q = 0; q < 4; ++q) {
    float4 xv = *(const float4*)(xr + q * 256 + l * 4);
    const float* wr = Wg + (size_t)(q * 256 + l * 4) * NEXP;
#pragma unroll
    for (int j = 0; j < 4; ++j) {
      float xs = j == 0 ? xv.x : j == 1 ? xv.y : j == 2 ? xv.z : xv.w;
      const float4* w4 = (const float4*)(wr + j * NEXP);
#pragma unroll
      for (int qq = 0; qq < 4; ++qq) {
        float4 w = w4[qq];
        acc[qq*4+0] += xs * w.x; acc[qq*4+1] += xs * w.y;
        acc[qq*4+2] += xs * w.z; acc[qq*4+3] += xs * w.w;
      }
    }
  }
#pragma unroll
  for (int e = 0; e < NEXP; ++e) {
    float v = acc[e];
#pragma unroll
    for (int off = 32; off > 0; off >>= 1) v += __shfl_xor(v, off, 64);
    acc[e] = v + bg[e];
  }
  if (l == 0) {
    int i1 = 0; float v1 = acc[0];
#pragma unroll
    for (int e = 1; e < NEXP; ++e) if (acc[e] > v1) { v1 = acc[e]; i1 = e; }
    int i2 = -1; float v2 = -1e30f;
#pragma unroll
    for (int e = 0; e < NEXP; ++e) if (e != i1 && acc[e] > v2) { v2 = acc[e]; i2 = e; }
    float e2 = __expf(v2 - v1);
    float inv = 1.f / (1.f + e2);
    a_e[n*2] = i1;   a_gate[n*2] = inv;
    a_e[n*2+1] = i2; a_gate[n*2+1] = e2 * inv;
  }
}

// ---------------- gate phase 2: per-expert slot assignment via LDS counter ----------------
__global__ __launch_bounds__(256) void assign_kernel(
    const int* __restrict__ a_e, int* __restrict__ a_slot,
    int* __restrict__ tok_of_slot, int* __restrict__ cnt)
{
  __shared__ int c;
  if (threadIdx.x == 0) c = 0;
  __syncthreads();
  int eid = blockIdx.x;
  for (int j = threadIdx.x; j < N_TOK * 2; j += 256) {
    if (a_e[j] == eid) {
      int p = atomicAdd(&c, 1);
      a_slot[j] = p;
      if (p < CAP) tok_of_slot[eid * CAP + p] = j >> 1;
    }
  }
  __syncthreads();
  if (threadIdx.x == 0) cnt[eid] = c;
}

// ---------------- gather: x rows -> bf16 blocked A-images [e][mt:8][kt:32][128 rows][32k swz] ----------------
__global__ __launch_bounds__(256) void gather_kernel(
    const float* __restrict__ x, const int* __restrict__ cnt,
    const int* __restrict__ tok_of_slot, unsigned short* __restrict__ Xe)
{
  int rid = blockIdx.x * 2 + (threadIdx.x >> 7);
  int tl = threadIdx.x & 127;
  int e = rid >> 10, slot = rid & (CAP - 1);
  int c = cnt[e]; if (c > CAP) c = CAP;
  if (slot >= c) return;
  int tok = tok_of_slot[rid];
  const float4* xs = (const float4*)(x + (size_t)tok * DMODEL + tl * 8);
  float4 u = xs[0], v = xs[1];
  us8 p;
  p[0]=f2bf(u.x); p[1]=f2bf(u.y); p[2]=f2bf(u.z); p[3]=f2bf(u.w);
  p[4]=f2bf(v.x); p[5]=f2bf(v.y); p[6]=f2bf(v.z); p[7]=f2bf(v.w);
  int kt = tl >> 2, cs = tl & 3;
  int row = slot & 127, mt = slot >> 7;
  int ps = cs ^ SIG(row);
  size_t off = ((size_t)((e*8 + mt)*32 + kt)) * 4096 + (size_t)row*32 + ps*8;
  *(us8*)&Xe[off] = p;
}

// ---------------- grouped GEMM: 128x128 tile, 4 waves, K-step 32, 32KB LDS ----------------
// A: blocked bf16 images [e][mt:8][kt:KTB][128][32k swz] via global_load_lds (linear)
// B: W row-major f32 [e][KTB*32][LDW], reg-staged -> bf16 swizzled LDS image [128 n][32k]
template<int KTB, int NTILES, bool GELU, bool OUT_BLOCKED>
__global__ __launch_bounds__(256, 4) void gemm_kernel(
    const unsigned short* __restrict__ Ablk, const float* __restrict__ W,
    unsigned short* __restrict__ OutU, const float* __restrict__ bias, const int* __restrict__ cnt)
{
  constexpr int LDW = NTILES * 128;
  constexpr int NWORK = NEXP * NTILES * 8;
  __shared__ __align__(16) char smem[32768];  // A dbuf 2x8K | B dbuf 2x8K
  int bid = blockIdx.x;
  int item = (bid & 7) * (NWORK / 8) + (bid >> 3);     // XCD-chunked
  int e = item / (NTILES * 8), rem = item % (NTILES * 8);
  int nt = rem >> 3, mt = rem & 7;                      // mt innermost: B-slab reuse
  int mcnt = cnt[e]; if (mcnt > CAP) mcnt = CAP;
  if (mt * 128 >= mcnt) return;
  int t = threadIdx.x, l = t & 63, wid = t >> 6;
  int wm = wid >> 1, wn = wid & 1;
  int rA = l & 15, g = l >> 4;
  int sw = (g ^ SIG(rA)) << 4;
  int aBase = (wm * 64 + rA) * 64;
  int bBase = (wn * 64 + rA) * 64;

  // ---- B staging: thread -> n row t&127, k half (t>>7)*16 ----
  int brow = t & 127, bkh = t >> 7;
  int sigb = SIG(brow);
  const float* wbase = W + (size_t)e * (KTB * 32) * LDW + (size_t)nt * 128 + brow;
  float br[16];
  auto loadB = [&](int kt) {
    const float* p = wbase + (size_t)(kt * 32 + bkh * 16) * LDW;
#pragma unroll
    for (int j = 0; j < 16; ++j) br[j] = p[(size_t)j * LDW];
  };
  auto writeB = [&](int bv) {
    char* lB = smem + 16384 + bv * 8192;
#pragma unroll
    for (int ci = 0; ci < 2; ++ci) {
      int c = bkh * 2 + ci;
      us8 p8;
#pragma unroll
      for (int j = 0; j < 8; ++j) p8[j] = f2bf(br[ci * 8 + j]);
      *(us8*)(lB + brow * 64 + ((c ^ sigb) << 4)) = p8;
    }
  };
  auto stageA = [&](int bv, int kt) {
    const unsigned short* s = Ablk + ((size_t)(e * 8 + mt) * KTB + kt) * 4096;
    char* lA = smem + bv * 8192;
    load_lds16(s + t * 8,        lA + wid * 1024);
    load_lds16(s + 2048 + t * 8, lA + 4096 + wid * 1024);
  };

  f32x4 acc[4][4] = {};

  loadB(0); stageA(0, 0); writeB(0);
  __syncthreads();

  int buf = 0;
  for (int kt = 0; kt < KTB; ++kt) {
    bool more = (kt + 1 < KTB);
    if (more) { loadB(kt + 1); stageA(buf ^ 1, kt + 1); }  // issue-early
    const char* bA = smem + buf * 8192 + aBase + sw;
    const char* bB = smem + 16384 + buf * 8192 + bBase + sw;
    frag8 bfr[4];
#pragma unroll
    for (int n16 = 0; n16 < 4; ++n16) bfr[n16] = *(const frag8*)(bB + n16 * 1024);
    __builtin_amdgcn_s_setprio(1);
#pragma unroll
    for (int m16 = 0; m16 < 4; ++m16) {
      frag8 a0 = *(const frag8*)(bA + m16 * 1024);
#pragma unroll
      for (int n16 = 0; n16 < 4; ++n16)
        acc[m16][n16] = __builtin_amdgcn_mfma_f32_16x16x32_bf16(a0, bfr[n16], acc[m16][n16], 0, 0, 0);
    }
    __builtin_amdgcn_s_setprio(0);
    if (more) writeB(buf ^ 1);                             // write-late
    __syncthreads();
    buf ^= 1;
  }

  float bv[4];
#pragma unroll
  for (int n16 = 0; n16 < 4; ++n16)
    bv[n16] = bias[e * LDW + nt * 128 + wn * 64 + n16 * 16 + rA];

  char* wb = smem + wid * 8192;          // per-wave 8KB bounce (smem dead after last barrier)
  if (OUT_BLOCKED) {
    // gelu -> bf16 -> 2 sub-images [64 rows][32k swz] -> hB blocked [e][mt][kt:KTB*2... (KTOT/32)][128][32k]
#pragma unroll
    for (int m16 = 0; m16 < 4; ++m16)
#pragma unroll
      for (int n16 = 0; n16 < 4; ++n16)
#pragma unroll
        for (int rr = 0; rr < 4; ++rr) {
          float xv = acc[m16][n16][rr] + bv[n16];
          if (GELU) {
            float u = 0.7978845608028654f * (xv + 0.044715f * xv * xv * xv);
            xv = xv / (1.f + __expf(-2.f * u));   // x*sigmoid(2u) == gelu_tanh
          }
          int row = m16 * 16 + g * 4 + rr;        // 0..63 local
          int col = n16 * 16 + rA;                // 0..63 local
          int si = col >> 5, c = (col >> 3) & 3, j = rA & 7;
          *(unsigned short*)(wb + si * 4096 + row * 64 + ((c ^ SIG(row)) << 4) + j * 2) = f2bf(xv);
        }
    asm volatile("s_waitcnt lgkmcnt(0)" ::: "memory");
    // copy out: sub-image si -> global kt-image (nt*4 + wn*2 + si), rows wm*64..
#pragma unroll
    for (int si = 0; si < 2; ++si) {
      size_t ib = ((size_t)(e * 8 + mt) * (NTILES * 4) + (nt * 4 + wn * 2 + si)) * 4096
                  + wm * 2048;
#pragma unroll
      for (int it = 0; it < 4; ++it) {
        us8 v = *(const us8*)(wb + si * 4096 + it * 1024 + l * 16);
        *(us8*)&OutU[ib + it * 512 + l * 8] = v;
      }
    }
  } else {
    // ye bf16 linear [e][CAP][1024]; bounce [64 rows][64 cols]
#pragma unroll
    for (int m16 = 0; m16 < 4; ++m16)
#pragma unroll
      for (int n16 = 0; n16 < 4; ++n16)
#pragma unroll
        for (int rr = 0; rr < 4; ++rr) {
          int row = m16 * 16 + g * 4 + rr;
          int col = n16 * 16 + rA;
          *(unsigned short*)(wb + row * 128 + col * 2) = f2bf(acc[m16][n16][rr] + bv[n16]);
        }
    asm volatile("s_waitcnt lgkmcnt(0)" ::: "memory");
#pragma unroll
    for (int it = 0; it < 8; ++it) {
      int row = it * 8 + (l >> 3);
      us8 v = *(const us8*)(wb + it * 1024 + (l >> 3) * 128 + (l & 7) * 16);
      *(us8*)&OutU[(size_t)(e * CAP + mt * 128 + wm * 64 + row) * 1024
                   + nt * 128 + wn * 64 + (l & 7) * 8] = v;
    }
  }
}

// ---------------- combine: out[n] = g0*ye[e0][s0] + g1*ye[e1][s1] (ye bf16) ----------------
__global__ __launch_bounds__(256) void combine_kernel(
    const unsigned short* __restrict__ ye, const int* __restrict__ a_e,
    const int* __restrict__ a_slot, const float* __restrict__ a_gate, float* __restrict__ out)
{
  int n = blockIdx.x, t = threadIdx.x;
  int e0 = a_e[n*2], e1 = a_e[n*2+1];
  int s0 = a_slot[n*2], s1 = a_slot[n*2+1];
  float g0 = a_gate[n*2], g1 = a_gate[n*2+1];
  float r[4] = {0.f, 0.f, 0.f, 0.f};
  if (s0 < CAP) {
    const unsigned short* p = &ye[(size_t)(e0*CAP + s0)*DMODEL + t*4];
    ushort4 v = *(const ushort4*)p;
    r[0] += g0*bf2f(v.x); r[1] += g0*bf2f(v.y); r[2] += g0*bf2f(v.z); r[3] += g0*bf2f(v.w);
  }
  if (s1 < CAP) {
    const unsigned short* p = &ye[(size_t)(e1*CAP + s1)*DMODEL + t*4];
    ushort4 v = *(const ushort4*)p;
    r[0] += g1*bf2f(v.x); r[1] += g1*bf2f(v.y); r[2] += g1*bf2f(v.z); r[3] += g1*bf2f(v.w);
  }
  float4 o; o.x = r[0]; o.y = r[1]; o.z = r[2]; o.w = r[3];
  *(float4*)&out[(size_t)n*DMODEL + t*4] = o;
}

extern "C" void kernel_launch(void* const* d_in, const int* in_sizes, int n_in,
                              void* d_out, int out_size, void* d_ws, size_t ws_size,
                              hipStream_t stream) {
  const float* x  = (const float*)d_in[0];
  const float* Wg = (const float*)d_in[1];
  const float* bg = (const float*)d_in[2];
  const float* W1 = (const float*)d_in[3];
  const float* b1 = (const float*)d_in[4];
  const float* W2 = (const float*)d_in[5];
  const float* b2 = (const float*)d_in[6];
  float* out = (float*)d_out;
  char* ws = (char*)d_ws;

  // workspace (~128MB + tables)
  unsigned short* Xe = (unsigned short*)(ws);                  // 33,554,432 B  [e][8][32][128][32]
  unsigned short* hB = (unsigned short*)(ws + 33554432);       // 67,108,864 B  [e][8][64][128][32]
  unsigned short* ye = (unsigned short*)(ws + 100663296);      // 33,554,432 B  [e][CAP][1024] bf16
  int* cnt           = (int*)(ws + 134217728);                 // 64 B
  int* tok           = (int*)(ws + 134217792);                 // 65,536 B
  int* a_e           = (int*)(ws + 134283328);                 // 32,768 B
  int* a_slot        = (int*)(ws + 134316096);                 // 32,768 B
  float* a_gate      = (float*)(ws + 134348864);               // 32,768 B

  gate_logits_kernel<<<1024, 256, 0, stream>>>(x, Wg, bg, a_e, a_gate);
  assign_kernel<<<16, 256, 0, stream>>>(a_e, a_slot, tok, cnt);
  gather_kernel<<<8192, 256, 0, stream>>>(x, cnt, tok, Xe);
  // gemm1: Xe x W1[e][1024][2048] -> hB blocked bf16 + gelu; K-steps 32
  gemm_kernel<32, 16, true,  true ><<<2048, 256, 0, stream>>>(Xe, W1, hB, b1, cnt);
  // gemm2: hB x W2[e][2048][1024] -> ye bf16 linear; K-steps 64
  gemm_kernel<64, 8,  false, false><<<1024, 256, 0, stream>>>(hB, W2, ye, b2, cnt);
  combine_kernel<<<4096, 256, 0, stream>>>(ye, a_e, a_slot, a_gate, out);
}

// Round 8
// 254.675 us; speedup vs baseline: 1.4063x; 1.1199x over previous
//
#include <hip/hip_runtime.h>

#define N_TOK 4096
#define DMODEL 1024
#define NEXP 16
#define HDIM 2048
#define CAP 1024
// swizzle: phys 16B-slot within 64B row = content_slot ^ SIG(row); bits 1-2 of row
#define SIG(row) (((row) >> 1) & 3)

typedef __attribute__((ext_vector_type(8))) short frag8;      // 8 bf16 MFMA operand
typedef __attribute__((ext_vector_type(4))) float f32x4;      // MFMA accumulator
typedef __attribute__((ext_vector_type(8))) unsigned short us8;

__device__ __forceinline__ unsigned short f2bf(float x) {
  unsigned u = __builtin_bit_cast(unsigned, x);
  u += 0x7fffu + ((u >> 16) & 1u);           // RNE
  return (unsigned short)(u >> 16);
}
__device__ __forceinline__ float bf2f(unsigned short b) {
  unsigned u = ((unsigned)b) << 16;
  return __builtin_bit_cast(float, u);
}
__device__ __forceinline__ void load_lds16(const void* g, void* l) {
  __builtin_amdgcn_global_load_lds((const __attribute__((address_space(1))) void*)g,
                                   (__attribute__((address_space(3))) void*)l, 16, 0, 0);
}

// ---------------- gate phase 1: logits -> top2 -> softmax (NO atomics) ----------------
__global__ __launch_bounds__(256) void gate_logits_kernel(
    const float* __restrict__ x, const float* __restrict__ Wg, const float* __restrict__ bg,
    int* __restrict__ a_e, float* __restrict__ a_gate)
{
  int wid = threadIdx.x >> 6, l = threadIdx.x & 63;
  int n = blockIdx.x * 4 + wid;
  const float* xr = x + (size_t)n * DMODEL;
  float acc[NEXP];
#pragma unroll
  for (int e = 0; e < NEXP; ++e) acc[e] = 0.f;
#pragma unroll
  for (int q = 0; q < 4; ++q) {
    float4 xv = *(const float4*)(xr + q * 256 + l * 4);
    const float* wr = Wg + (size_t)(q * 256 + l * 4) * NEXP;
#pragma unroll
    for (int j = 0; j < 4; ++j) {
      float xs = j == 0 ? xv.x : j == 1 ? xv.y : j == 2 ? xv.z : xv.w;
      const float4* w4 = (const float4*)(wr + j * NEXP);
#pragma unroll
      for (int qq = 0; qq < 4; ++qq) {
        float4 w = w4[qq];
        acc[qq*4+0] += xs * w.x; acc[qq*4+1] += xs * w.y;
        acc[qq*4+2] += xs * w.z; acc[qq*4+3] += xs * w.w;
      }
    }
  }
#pragma unroll
  for (int e = 0; e < NEXP; ++e) {
    float v = acc[e];
#pragma unroll
    for (int off = 32; off > 0; off >>= 1) v += __shfl_xor(v, off, 64);
    acc[e] = v + bg[e];
  }
  if (l == 0) {
    int i1 = 0; float v1 = acc[0];
#pragma unroll
    for (int e = 1; e < NEXP; ++e) if (acc[e] > v1) { v1 = acc[e]; i1 = e; }
    int i2 = -1; float v2 = -1e30f;
#pragma unroll
    for (int e = 0; e < NEXP; ++e) if (e != i1 && acc[e] > v2) { v2 = acc[e]; i2 = e; }
    float e2 = __expf(v2 - v1);
    float inv = 1.f / (1.f + e2);
    a_e[n*2] = i1;   a_gate[n*2] = inv;
    a_e[n*2+1] = i2; a_gate[n*2+1] = e2 * inv;
  }
}

// ---------------- gate phase 2: per-expert slot assignment via LDS counter ----------------
__global__ __launch_bounds__(256) void assign_kernel(
    const int* __restrict__ a_e, int* __restrict__ a_slot,
    int* __restrict__ tok_of_slot, int* __restrict__ cnt)
{
  __shared__ int c;
  if (threadIdx.x == 0) c = 0;
  __syncthreads();
  int eid = blockIdx.x;
  for (int j = threadIdx.x; j < N_TOK * 2; j += 256) {
    if (a_e[j] == eid) {
      int p = atomicAdd(&c, 1);
      a_slot[j] = p;
      if (p < CAP) tok_of_slot[eid * CAP + p] = j >> 1;
    }
  }
  __syncthreads();
  if (threadIdx.x == 0) cnt[eid] = c;
}

// ---------------- gather: x rows -> bf16 blocked A-images [e][mi:8][kt:32][128][32k swz] ----------------
__global__ __launch_bounds__(256) void gather_kernel(
    const float* __restrict__ x, const int* __restrict__ cnt,
    const int* __restrict__ tok_of_slot, unsigned short* __restrict__ Xe)
{
  int rid = blockIdx.x * 2 + (threadIdx.x >> 7);
  int tl = threadIdx.x & 127;
  int e = rid >> 10, slot = rid & (CAP - 1);
  int c = cnt[e]; if (c > CAP) c = CAP;
  if (slot >= c) return;
  int tok = tok_of_slot[rid];
  const float4* xs = (const float4*)(x + (size_t)tok * DMODEL + tl * 8);
  float4 u = xs[0], v = xs[1];
  us8 p;
  p[0]=f2bf(u.x); p[1]=f2bf(u.y); p[2]=f2bf(u.z); p[3]=f2bf(u.w);
  p[4]=f2bf(v.x); p[5]=f2bf(v.y); p[6]=f2bf(v.z); p[7]=f2bf(v.w);
  int kt = tl >> 2, cs = tl & 3;
  int row = slot & 127, mi = slot >> 7;
  int ps = cs ^ SIG(row);
  size_t off = ((size_t)((e*8 + mi)*32 + kt)) * 4096 + (size_t)row*32 + ps*8;
  *(us8*)&Xe[off] = p;
}

// ---------------- grouped GEMM: 256xBN tile, 8 waves (2Mx4N), K-step 32 ----------------
// A: blocked bf16 images [e][mi:8][kt:KTB][128][32k swz], staged linear via global_load_lds
// B: W row-major f32 [e][KTB*32][LDW], reg-staged 2 steps ahead -> bf16 swizzled LDS
// Pipeline: counted vmcnt(8), raw s_barrier, 1 barrier/K-step. VMEM issue order PINNED
// with sched_barrier(0) (the vmcnt contract requires stageA issued before loadB).
template<int KTB, int BN, int LDW, bool GELU, bool OUT_BLOCKED>
__global__ __launch_bounds__(512, 2) void gemm_kernel(
    const unsigned short* __restrict__ Ablk, const float* __restrict__ W,
    unsigned short* __restrict__ OutU, const float* __restrict__ bias,
    const int* __restrict__ cnt)
{
  constexpr int NT = LDW / BN;             // n-tiles
  constexpr int BBYTES = BN * 64;          // B LDS image bytes (BN rows x 64B)
  constexpr int WNW = BN / 4;              // wave n-width (64 or 32)
  constexpr int NN = WNW / 16;             // n16 frags per wave (4 or 2)
  __shared__ __align__(16) char smem[65536];   // A dbuf 2x16K @0 | B dbuf 2xBBYTES @32K
  constexpr int NBLK = NEXP * NT * 4;
  int bid = blockIdx.x;
  int item = (bid & 7) * (NBLK / 8) + (bid >> 3);   // XCD-chunked
  int e = item >> 5, rem = item & 31;
  int nt = rem >> 2, mtg = rem & 3;                 // mtg innermost: B-slab L2 reuse
  int mcnt = cnt[e]; if (mcnt > CAP) mcnt = CAP;
  if (mtg * 256 >= mcnt) return;
  int t = threadIdx.x, l = t & 63, w = t >> 6;
  int wm = w >> 2, wn = w & 3;
  int rA = l & 15, g = l >> 4;
  int swz = (g ^ SIG(rA)) << 4;
  int aOff = wm * 8192 + rA * 64;
  int bOff = (wn * WNW + rA) * 64;

  // B staging thread map: 512 threads cover BN rows x 32 k f32 (16KB or 8KB)
  int b_r0 = (BN == 256) ? 2 * (t & 127) : (t & 127);
  int b_k0 = (t >> 7) * 8;
  int sig0 = SIG(b_r0), sig1 = SIG(b_r0 + 1);
  int bslot = b_k0 >> 3;
  const float* wsrc = W + (size_t)e * (KTB * 32) * LDW + nt * BN + b_r0;
  const unsigned short* abase = Ablk + (size_t)(e * 8 + mtg * 2) * KTB * 4096;

  float2 br0[8], br1[8];        // named double reg-buffer (rule #20: no runtime idx)

  auto loadB = [&](float2 (&br)[8], int kt) {
    const float* p = wsrc + (size_t)(kt * 32 + b_k0) * LDW;
#pragma unroll
    for (int j = 0; j < 8; ++j) {
      if constexpr (BN == 256) br[j] = *(const float2*)(p + (size_t)j * LDW);
      else                     br[j].x = p[(size_t)j * LDW];
    }
  };
  auto writeB = [&](float2 (&br)[8], char* lB) {
    us8 p8;
#pragma unroll
    for (int j = 0; j < 8; ++j) p8[j] = f2bf(br[j].x);
    *(us8*)(lB + b_r0 * 64 + ((bslot ^ sig0) << 4)) = p8;
    if constexpr (BN == 256) {
      us8 q8;
#pragma unroll
      for (int j = 0; j < 8; ++j) q8[j] = f2bf(br[j].y);
      *(us8*)(lB + (b_r0 + 1) * 64 + ((bslot ^ sig1) << 4)) = q8;
    }
  };
  auto stageA = [&](char* lA, int kt) {                 // 2 x global_load_lds (8KB each)
    load_lds16(abase + (size_t)kt * 4096 + t * 8,         lA + w * 1024);
    load_lds16(abase + (size_t)(KTB + kt) * 4096 + t * 8, lA + 8192 + w * 1024);
  };

  f32x4 acc[8][NN] = {};

  // ---- prologue: fill LDS0 with tile0; regs: br1=B1 (arrived), br0=B2 (in flight) ----
  loadB(br0, 0);                                         // VMEM 1-8
  __builtin_amdgcn_sched_barrier(0);
  stageA(smem, 0);                                       // VMEM 9-10
  __builtin_amdgcn_sched_barrier(0);
  loadB(br1, 1);                                         // VMEM 11-18
  __builtin_amdgcn_sched_barrier(0);
  asm volatile("s_waitcnt vmcnt(10)" ::: "memory");      // B0 (1-8) arrived
  writeB(br0, smem + 32768);
  loadB(br0, 2);                                         // VMEM 19-26
  __builtin_amdgcn_sched_barrier(0);
  asm volatile("s_waitcnt vmcnt(8)" ::: "memory");       // A0 + B1 done; B2 in flight
  asm volatile("s_waitcnt lgkmcnt(0)" ::: "memory");
  __builtin_amdgcn_sched_barrier(0);
  __builtin_amdgcn_s_barrier();
  __builtin_amdgcn_sched_barrier(0);

  // ---- steady loop: step kt: buf=kt&1; writes B(kt+1); loads B(kt+3); computes cur ----
#define GSTEP(KT, BUF, BRW)  do {                                              \
    int kA = ((KT) + 1 < KTB) ? (KT) + 1 : KTB - 1;                            \
    int kL = ((KT) + 3 < KTB) ? (KT) + 3 : KTB - 1;                            \
    stageA(smem + (((BUF) ^ 1) * 16384), kA);                                  \
    __builtin_amdgcn_sched_barrier(0);  /* pin: stageA before loadB in vmcnt */\
    writeB(BRW, smem + 32768 + ((BUF) ^ 1) * BBYTES);                          \
    loadB(BRW, kL);                                                            \
    __builtin_amdgcn_sched_barrier(0);  /* pin: loadB issued here, not later */\
    const char* lA = smem + (BUF) * 16384 + aOff + swz;                        \
    const char* lB = smem + 32768 + (BUF) * BBYTES + bOff + swz;               \
    frag8 bfr[NN];                                                             \
    _Pragma("unroll")                                                          \
    for (int n16 = 0; n16 < NN; ++n16)                                         \
      bfr[n16] = *(const frag8*)(lB + n16 * 1024);                             \
    __builtin_amdgcn_s_setprio(1);                                             \
    _Pragma("unroll")                                                          \
    for (int m16 = 0; m16 < 8; ++m16) {                                        \
      frag8 a0 = *(const frag8*)(lA + m16 * 1024);                             \
      _Pragma("unroll")                                                        \
      for (int n16 = 0; n16 < NN; ++n16)                                       \
        acc[m16][n16] = __builtin_amdgcn_mfma_f32_16x16x32_bf16(               \
            a0, bfr[n16], acc[m16][n16], 0, 0, 0);                             \
    }                                                                          \
    __builtin_amdgcn_s_setprio(0);                                             \
    asm volatile("s_waitcnt vmcnt(8)" ::: "memory");                           \
    asm volatile("s_waitcnt lgkmcnt(0)" ::: "memory");                         \
    __builtin_amdgcn_sched_barrier(0);                                         \
    __builtin_amdgcn_s_barrier();                                              \
    __builtin_amdgcn_sched_barrier(0);                                         \
  } while (0)

  for (int kt = 0; kt < KTB; kt += 2) {
    GSTEP(kt, 0, br1);
    GSTEP(kt + 1, 1, br0);
  }
#undef GSTEP

  float bv[NN];
#pragma unroll
  for (int n16 = 0; n16 < NN; ++n16)
    bv[n16] = bias[e * LDW + nt * BN + wn * WNW + n16 * 16 + rA];

  char* wb = smem + w * 8192;                 // per-wave 8KB bounce; LDS dead after loop
  if constexpr (OUT_BLOCKED) {
    // gelu -> bf16 -> per-si 128x32 swizzled image -> blocked out [e][mi:8][LDW/32][128][32]
#pragma unroll
    for (int si = 0; si < NN / 2; ++si) {
#pragma unroll
      for (int m16 = 0; m16 < 8; ++m16)
#pragma unroll
        for (int n2 = 0; n2 < 2; ++n2) {
          int n16 = si * 2 + n2;
#pragma unroll
          for (int rr = 0; rr < 4; ++rr) {
            float xv = acc[m16][n16][rr] + bv[n16];
            if (GELU) {
              float u = 0.7978845608028654f * (xv + 0.044715f * xv * xv * xv);
              xv = xv / (1.f + __expf(-2.f * u));     // x*sigmoid(2u) == gelu_tanh
            }
            int row = m16 * 16 + g * 4 + rr;          // 0..127
            int k = n2 * 16 + rA;                     // 0..31
            int c = k >> 3, j = k & 7;
            *(unsigned short*)(wb + row * 64 + ((c ^ SIG(row)) << 4) + j * 2) = f2bf(xv);
          }
        }
      asm volatile("s_waitcnt lgkmcnt(0)" ::: "memory");
      size_t ib = ((size_t)(e * 8 + mtg * 2 + wm) * (LDW / 32)
                   + nt * (BN / 32) + wn * (WNW / 32) + si) * 4096;
#pragma unroll
      for (int it = 0; it < 8; ++it)
        *(us8*)&OutU[ib + it * 512 + l * 8] = *(const us8*)(wb + it * 1024 + l * 16);
    }
  } else {
    // linear bf16 out [e][CAP][LDW]; bounce [128 rows][32 cols]
#pragma unroll
    for (int m16 = 0; m16 < 8; ++m16)
#pragma unroll
      for (int n16 = 0; n16 < NN; ++n16)
#pragma unroll
        for (int rr = 0; rr < 4; ++rr) {
          int row = m16 * 16 + g * 4 + rr;
          int colb = n16 * 16 + rA;
          *(unsigned short*)(wb + row * 64 + colb * 2) = f2bf(acc[m16][n16][rr] + bv[n16]);
        }
    asm volatile("s_waitcnt lgkmcnt(0)" ::: "memory");
#pragma unroll
    for (int it = 0; it < 8; ++it) {
      int row = it * 16 + (l >> 2);
      *(us8*)&OutU[(size_t)(e * CAP + mtg * 256 + wm * 128 + row) * LDW
                   + nt * BN + wn * WNW + (l & 3) * 8]
          = *(const us8*)(wb + it * 1024 + l * 16);
    }
  }
}

// ---------------- combine: out[n] = g0*ye[e0][s0] + g1*ye[e1][s1] (ye bf16) ----------------
__global__ __launch_bounds__(256) void combine_kernel(
    const unsigned short* __restrict__ ye, const int* __restrict__ a_e,
    const int* __restrict__ a_slot, const float* __restrict__ a_gate, float* __restrict__ out)
{
  int n = blockIdx.x, t = threadIdx.x;
  int e0 = a_e[n*2], e1 = a_e[n*2+1];
  int s0 = a_slot[n*2], s1 = a_slot[n*2+1];
  float g0 = a_gate[n*2], g1 = a_gate[n*2+1];
  float r[4] = {0.f, 0.f, 0.f, 0.f};
  if (s0 < CAP) {
    ushort4 v = *(const ushort4*)&ye[(size_t)(e0*CAP + s0)*DMODEL + t*4];
    r[0] += g0*bf2f(v.x); r[1] += g0*bf2f(v.y); r[2] += g0*bf2f(v.z); r[3] += g0*bf2f(v.w);
  }
  if (s1 < CAP) {
    ushort4 v = *(const ushort4*)&ye[(size_t)(e1*CAP + s1)*DMODEL + t*4];
    r[0] += g1*bf2f(v.x); r[1] += g1*bf2f(v.y); r[2] += g1*bf2f(v.z); r[3] += g1*bf2f(v.w);
  }
  float4 o; o.x = r[0]; o.y = r[1]; o.z = r[2]; o.w = r[3];
  *(float4*)&out[(size_t)n*DMODEL + t*4] = o;
}

extern "C" void kernel_launch(void* const* d_in, const int* in_sizes, int n_in,
                              void* d_out, int out_size, void* d_ws, size_t ws_size,
                              hipStream_t stream) {
  const float* x  = (const float*)d_in[0];
  const float* Wg = (const float*)d_in[1];
  const float* bg = (const float*)d_in[2];
  const float* W1 = (const float*)d_in[3];
  const float* b1 = (const float*)d_in[4];
  const float* W2 = (const float*)d_in[5];
  const float* b2 = (const float*)d_in[6];
  float* out = (float*)d_out;
  char* ws = (char*)d_ws;

  // workspace (~128MB + tables)
  unsigned short* Xe = (unsigned short*)(ws);                  // 33,554,432 B [16][8][32][4096]
  unsigned short* hB = (unsigned short*)(ws + 33554432);       // 67,108,864 B [16][8][64][4096]
  unsigned short* ye = (unsigned short*)(ws + 100663296);      // 33,554,432 B [16][CAP][1024]
  int* cnt           = (int*)(ws + 134217728);                 // 64 B
  int* tok           = (int*)(ws + 134217792);                 // 65,536 B
  int* a_e           = (int*)(ws + 134283328);                 // 32,768 B
  int* a_slot        = (int*)(ws + 134316096);                 // 32,768 B
  float* a_gate      = (float*)(ws + 134348864);               // 32,768 B

  gate_logits_kernel<<<1024, 256, 0, stream>>>(x, Wg, bg, a_e, a_gate);
  assign_kernel<<<16, 256, 0, stream>>>(a_e, a_slot, tok, cnt);
  gather_kernel<<<8192, 256, 0, stream>>>(x, cnt, tok, Xe);
  // gemm1: Xe x W1[e][1024][2048] -> hB blocked bf16 + gelu; 256x256 tile, 32 K-steps
  gemm_kernel<32, 256, 2048, true,  true ><<<512, 512, 0, stream>>>(Xe, W1, hB, b1, cnt);
  // gemm2: hB x W2[e][2048][1024] -> ye bf16 linear; 256x128 tile, 64 K-steps
  gemm_kernel<64, 128, 1024, false, false><<<512, 512, 0, stream>>>(hB, W2, ye, b2, cnt);
  combine_kernel<<<4096, 256, 0, stream>>>(ye, a_e, a_slot, a_gate, out);
}